// Round 8
// baseline (337.412 us; speedup 1.0000x reference)
//
#include <hip/hip_runtime.h>
#include <hip/hip_bf16.h>
#include <stdint.h>

// ---------------------------------------------------------------------------
// LSTM cell, fused as one bf16 MFMA GEMM:
//   A  = [input | hidden]            : [16384][2048]  (bf16, packed in ws)
//   W  = [Wx[g] | Wh[g]] per gate g  : [4096][2048]   (bf16, packed in ws, [N][K])
//   pre[g][b][s] = sum_k A[b][k] * W[g*1024+s][k] + bias[g][s]
//
// Round 8: 8-phase schedule (m201 template adapted). r7's coarse 2-phase
// double-buffer was neutral (39% MfmaUtil, 887 TF = the 2-phase ceiling);
// the missing lever is the fine per-phase interleave (m196/m218).
//   * tile 256r x 64s x 4g (== 256x256), BK=64, 8 waves 2M x 4N:
//     per-wave 128r x 16s x 4g, acc[4][8] f32x4 = 128 regs.
//   * LDS 2 dbuf x 4 half-tiles {Ah0,Ah1,Wg01,Wg23} x 16KB = 128KB.
//   * per K-tile 4 phases: {ds_read subtile || stage 1 half (2 GLD16) ->
//     counted vmcnt at phases 0,3 only -> barrier -> setprio(1) -> 16 MFMA
//     -> setprio(0) -> barrier}. Guarantee ordering: p3's vmcnt(2) covers
//     next tile's {Ah0,Ah1,Wg01}; p0's vmcnt(2) covers Wg23. Never 0
//     mid-loop.
//   * XCD remap col-tile-major: per-XCD W set = 1MB < 4MB L2 so the
//     1-phase-slack W loads are L2 hits; A streams (3-phase slack).
// ---------------------------------------------------------------------------

typedef short bf16x8 __attribute__((ext_vector_type(8)));
typedef float f32x4 __attribute__((ext_vector_type(4)));

#define B_ROWS 16384
#define D_K 2048

__device__ __forceinline__ unsigned short f2bf(float f) {
    unsigned u = __builtin_bit_cast(unsigned, f);
    u += 0x7FFFu + ((u >> 16) & 1u);   // round-to-nearest-even
    return (unsigned short)(u >> 16);
}

__device__ __forceinline__ float sigf(float x) { return 1.0f / (1.0f + __expf(-x)); }
__device__ __forceinline__ float tanhfast(float x) { return 2.0f / (1.0f + __expf(-2.0f * x)) - 1.0f; }

// global -> LDS direct copy, 16B per lane; LDS dest wave-uniform base + lane*16.
#define GLD16(gp, lp)                                                          \
    __builtin_amdgcn_global_load_lds(                                          \
        (const __attribute__((address_space(1))) unsigned int*)(gp),           \
        (__attribute__((address_space(3))) unsigned int*)(lp), 16, 0, 0)

#define FENCE() asm volatile("" ::: "memory")
#define BARRIER()                                                              \
    do { __builtin_amdgcn_s_barrier(); FENCE(); } while (0)

// --------------------------- pack kernels ----------------------------------

__global__ void pack_A_kernel(const float* __restrict__ x,
                              const float* __restrict__ h,
                              unsigned short* __restrict__ A) {
    const int total = B_ROWS * (D_K / 4);          // vec4 units, 512 per row
    for (int v = blockIdx.x * blockDim.x + threadIdx.x; v < total;
         v += gridDim.x * blockDim.x) {
        const int b = v >> 9;
        const int k0 = (v & 511) << 2;
        const float* src = (k0 < 1024) ? (x + (size_t)b * 1024 + k0)
                                       : (h + (size_t)b * 1024 + (k0 - 1024));
        float4 f = *(const float4*)src;
        unsigned p0 = (unsigned)f2bf(f.x) | ((unsigned)f2bf(f.y) << 16);
        unsigned p1 = (unsigned)f2bf(f.z) | ((unsigned)f2bf(f.w) << 16);
        uint2 o; o.x = p0; o.y = p1;
        *(uint2*)(A + (size_t)v * 4) = o;
    }
}

__global__ void pack_W_kernel(const float* __restrict__ Wx,
                              const float* __restrict__ Wh,
                              unsigned short* __restrict__ W) {
    const int total = 4096 * (D_K / 4);
    for (int v = blockIdx.x * blockDim.x + threadIdx.x; v < total;
         v += gridDim.x * blockDim.x) {
        const int n = v >> 9;                       // n = g*1024 + s
        const int k0 = (v & 511) << 2;
        const float* src = (k0 < 1024) ? (Wx + (size_t)n * 1024 + k0)
                                       : (Wh + (size_t)n * 1024 + (k0 - 1024));
        float4 f = *(const float4*)src;
        unsigned p0 = (unsigned)f2bf(f.x) | ((unsigned)f2bf(f.y) << 16);
        unsigned p1 = (unsigned)f2bf(f.z) | ((unsigned)f2bf(f.w) << 16);
        uint2 o; o.x = p0; o.y = p1;
        *(uint2*)(W + (size_t)v * 4) = o;
    }
}

__global__ void pack_bias_kernel(const float* __restrict__ bx,
                                 const float* __restrict__ bh,
                                 float* __restrict__ bias) {
    int i = blockIdx.x * blockDim.x + threadIdx.x;
    if (i < 4096) bias[i] = bx[i] + bh[i];
}

// --------------------------- fused GEMM ------------------------------------

__global__ __launch_bounds__(512, 2) void lstm_gemm_kernel(
    const unsigned short* __restrict__ A,     // [16384][2048]
    const unsigned short* __restrict__ W,     // [4096][2048]
    const float* __restrict__ bias,           // [4096]
    const float* __restrict__ cell,           // [16384][1024]
    float* __restrict__ out) {                // new_c then h, each [16384][1024]
    // [dbuf][half: Ah0,Ah1,Wg01,Wg23][16KB]; each half = 16 chunks of 1KB,
    // chunk = 8 rows x 64 elems (col pre-swizzled on the global side).
    __shared__ __align__(16) unsigned short smem[2][4][8192];

    // XCD remap, col-tile-major per XCD: XCD x owns wg in [x*128, x*128+128)
    // = 2 col-tiles x 64 row-stripes -> W working set 1MB, L2-resident.
    const int bid = blockIdx.x;
    const int wg = (bid & 7) * 128 + (bid >> 3);
    const int brow = (wg & 63) << 8;          // 64 row stripes of 256
    const int bcol = (wg >> 6) << 6;          // 16 col tiles of 64 (s in gate)

    const int tid = threadIdx.x;
    const int wid = tid >> 6;                 // 0..7
    const int lane = tid & 63;
    const int wr = wid >> 2;                  // 0..1: rows wr*128..+128
    const int wc = wid & 3;                   // 0..3: s-cols wc*16..+16
    const int lr = lane & 15, lg = lane >> 4;
    const int l8 = lane >> 3;                 // row within a 1KB chunk
    const int lcol = (((lane & 7) ^ l8) << 3);  // pre-swizzled global col

    f32x4 acc[4][8];
#pragma unroll
    for (int g = 0; g < 4; ++g)
#pragma unroll
        for (int m = 0; m < 8; ++m) acc[g][m] = (f32x4){0.f, 0.f, 0.f, 0.f};

    // staging sources: per half-tile this thread stages 2 chunks (2*wid, +1)
    const unsigned short* gpA[2][2];
#pragma unroll
    for (int ah = 0; ah < 2; ++ah)
#pragma unroll
        for (int i = 0; i < 2; ++i)
            gpA[ah][i] = A + (size_t)(brow + ah * 128 + (2 * wid + i) * 8 + l8) * D_K + lcol;
    const unsigned short* gpW[2][2];
#pragma unroll
    for (int wh = 0; wh < 2; ++wh)
#pragma unroll
        for (int i = 0; i < 2; ++i) {
            const int rw = (2 * wid + i) * 8 + l8;          // 0..127 in half
            gpW[wh][i] = W + (size_t)((2 * wh + (rw >> 6)) * 1024 + bcol + (rw & 63)) * D_K + lcol;
        }

#define STAGE_HALF(dbbase, half, gparr, kt)                                    \
    do {                                                                       \
        GLD16(gparr[0] + (kt), (dbbase) + (half) * 16384 + (2 * wid) * 1024);  \
        GLD16(gparr[1] + (kt), (dbbase) + (half) * 16384 + (2 * wid + 1) * 1024); \
    } while (0)

    // prologue: stage tile 0 into buf 0 in order Ah0,Ah1,Wg01,Wg23
    {
        char* db = (char*)smem[0][0];
        STAGE_HALF(db, 0, gpA[0], 0);
        STAGE_HALF(db, 1, gpA[1], 0);
        STAGE_HALF(db, 2, gpW[0], 0);
        STAGE_HALF(db, 3, gpW[1], 0);
        asm volatile("s_waitcnt vmcnt(2)" ::: "memory");  // Ah0,Ah1,Wg01 done
        BARRIER();
    }

    const int swk0 = (lg * 8) ^ ((lr & 7) << 3);          // kk=0 swizzled col
    const int swk1 = (32 + lg * 8) ^ ((lr & 7) << 3);     // kk=1

    bf16x8 a[8], w[4];

    for (int t = 0; t < 31; ++t) {
        const unsigned short* sb = smem[t & 1][0];
        char* db = (char*)smem[(t & 1) ^ 1][0];
        const int kt2 = (t + 1) * 64;

        // ---- phase 0: read A(kk0)+Wg01(kk0); stage Ah0(t+1); vmcnt covers Wg23(t)
#pragma unroll
        for (int m = 0; m < 8; ++m)
            a[m] = *(const bf16x8*)&sb[wr * 8192 + (m * 16 + lr) * 64 + swk0];
        w[0] = *(const bf16x8*)&sb[2 * 8192 + (wc * 16 + lr) * 64 + swk0];
        w[1] = *(const bf16x8*)&sb[2 * 8192 + (64 + wc * 16 + lr) * 64 + swk0];
        STAGE_HALF(db, 0, gpA[0], kt2);
        asm volatile("s_waitcnt vmcnt(2)" ::: "memory");
        BARRIER();
        __builtin_amdgcn_s_setprio(1);
#pragma unroll
        for (int m = 0; m < 8; ++m)
            acc[0][m] = __builtin_amdgcn_mfma_f32_16x16x32_bf16(a[m], w[0], acc[0][m], 0, 0, 0);
#pragma unroll
        for (int m = 0; m < 8; ++m)
            acc[1][m] = __builtin_amdgcn_mfma_f32_16x16x32_bf16(a[m], w[1], acc[1][m], 0, 0, 0);
        __builtin_amdgcn_s_setprio(0);
        FENCE();
        BARRIER();

        // ---- phase 1: read Wg23(kk0); stage Ah1(t+1); reuse a[] (kk0)
        w[2] = *(const bf16x8*)&sb[3 * 8192 + (wc * 16 + lr) * 64 + swk0];
        w[3] = *(const bf16x8*)&sb[3 * 8192 + (64 + wc * 16 + lr) * 64 + swk0];
        STAGE_HALF(db, 1, gpA[1], kt2);
        BARRIER();
        __builtin_amdgcn_s_setprio(1);
#pragma unroll
        for (int m = 0; m < 8; ++m)
            acc[2][m] = __builtin_amdgcn_mfma_f32_16x16x32_bf16(a[m], w[2], acc[2][m], 0, 0, 0);
#pragma unroll
        for (int m = 0; m < 8; ++m)
            acc[3][m] = __builtin_amdgcn_mfma_f32_16x16x32_bf16(a[m], w[3], acc[3][m], 0, 0, 0);
        __builtin_amdgcn_s_setprio(0);
        FENCE();
        BARRIER();

        // ---- phase 2: read A(kk1)+Wg01(kk1); stage Wg01(t+1)
#pragma unroll
        for (int m = 0; m < 8; ++m)
            a[m] = *(const bf16x8*)&sb[wr * 8192 + (m * 16 + lr) * 64 + swk1];
        w[0] = *(const bf16x8*)&sb[2 * 8192 + (wc * 16 + lr) * 64 + swk1];
        w[1] = *(const bf16x8*)&sb[2 * 8192 + (64 + wc * 16 + lr) * 64 + swk1];
        STAGE_HALF(db, 2, gpW[0], kt2);
        BARRIER();
        __builtin_amdgcn_s_setprio(1);
#pragma unroll
        for (int m = 0; m < 8; ++m)
            acc[0][m] = __builtin_amdgcn_mfma_f32_16x16x32_bf16(a[m], w[0], acc[0][m], 0, 0, 0);
#pragma unroll
        for (int m = 0; m < 8; ++m)
            acc[1][m] = __builtin_amdgcn_mfma_f32_16x16x32_bf16(a[m], w[1], acc[1][m], 0, 0, 0);
        __builtin_amdgcn_s_setprio(0);
        FENCE();
        BARRIER();

        // ---- phase 3: read Wg23(kk1); stage Wg23(t+1); vmcnt covers next
        //      tile's {Ah0,Ah1,Wg01} (leaves Wg23(t+1) in flight)
        w[2] = *(const bf16x8*)&sb[3 * 8192 + (wc * 16 + lr) * 64 + swk1];
        w[3] = *(const bf16x8*)&sb[3 * 8192 + (64 + wc * 16 + lr) * 64 + swk1];
        STAGE_HALF(db, 3, gpW[1], kt2);
        asm volatile("s_waitcnt vmcnt(2)" ::: "memory");
        BARRIER();
        __builtin_amdgcn_s_setprio(1);
#pragma unroll
        for (int m = 0; m < 8; ++m)
            acc[2][m] = __builtin_amdgcn_mfma_f32_16x16x32_bf16(a[m], w[2], acc[2][m], 0, 0, 0);
#pragma unroll
        for (int m = 0; m < 8; ++m)
            acc[3][m] = __builtin_amdgcn_mfma_f32_16x16x32_bf16(a[m], w[3], acc[3][m], 0, 0, 0);
        __builtin_amdgcn_s_setprio(0);
        FENCE();
        BARRIER();
    }

    // ---- tail: tile 31 in buf 1, nothing left to stage
    asm volatile("s_waitcnt vmcnt(0)" ::: "memory");
    BARRIER();
    {
        const unsigned short* sb = smem[1][0];
#pragma unroll
        for (int kk = 0; kk < 2; ++kk) {
            const int swk = (kk * 32 + lg * 8) ^ ((lr & 7) << 3);
#pragma unroll
            for (int m = 0; m < 8; ++m)
                a[m] = *(const bf16x8*)&sb[wr * 8192 + (m * 16 + lr) * 64 + swk];
#pragma unroll
            for (int g = 0; g < 4; ++g) {
                const bf16x8 wv = *(const bf16x8*)&sb[(2 + (g >> 1)) * 8192 + ((g & 1) * 64 + wc * 16 + lr) * 64 + swk];
#pragma unroll
                for (int m = 0; m < 8; ++m)
                    acc[g][m] = __builtin_amdgcn_mfma_f32_16x16x32_bf16(a[m], wv, acc[g][m], 0, 0, 0);
            }
        }
    }
#undef STAGE_HALF

    // fused epilogue: C/D layout col = lane&15, row = (lane>>4)*4 + reg
    float bv[4];
#pragma unroll
    for (int g = 0; g < 4; ++g) bv[g] = bias[(g << 10) + bcol + wc * 16 + lr];

    float* outc = out;
    float* outh = out + (size_t)B_ROWS * 1024;
#pragma unroll
    for (int m = 0; m < 8; ++m) {
#pragma unroll
        for (int r = 0; r < 4; ++r) {
            const int b = brow + wr * 128 + m * 16 + lg * 4 + r;
            const size_t idx = (size_t)b * 1024 + bcol + wc * 16 + lr;
            float pf = acc[0][m][r] + bv[0];
            float pi = acc[1][m][r] + bv[1];
            float pc = acc[2][m][r] + bv[2];
            float po = acc[3][m][r] + bv[3];
            float cl = cell[idx];
            float nc = cl * sigf(pf) + sigf(pi) * tanhfast(pc);
            outc[idx] = nc;
            outh[idx] = tanhfast(nc) * sigf(po);
        }
    }
}

// ------------------- fp32 fallback (ws too small; slow but correct) --------

__global__ void lstm_naive_kernel(const float* __restrict__ x,
                                  const float* __restrict__ cell,
                                  const float* __restrict__ h,
                                  const float* __restrict__ Wx,
                                  const float* __restrict__ bx,
                                  const float* __restrict__ Wh,
                                  const float* __restrict__ bh,
                                  float* __restrict__ out) {
    int idx = blockIdx.x * blockDim.x + threadIdx.x;
    if (idx >= B_ROWS * 1024) return;
    int b = idx >> 10, s = idx & 1023;
    const float* xr = x + (size_t)b * 1024;
    const float* hr = h + (size_t)b * 1024;
    float pre[4];
#pragma unroll
    for (int g = 0; g < 4; ++g) {
        float acc = bx[(g << 10) + s] + bh[(g << 10) + s];
        const float* wx = Wx + ((size_t)(g << 10) + s) * 1024;
        const float* wh = Wh + ((size_t)(g << 10) + s) * 1024;
        for (int k = 0; k < 1024; ++k) acc += xr[k] * wx[k] + hr[k] * wh[k];
        pre[g] = acc;
    }
    float nc = cell[idx] * sigf(pre[0]) + sigf(pre[1]) * tanhfast(pre[2]);
    out[idx] = nc;
    out[(size_t)B_ROWS * 1024 + idx] = tanhfast(nc) * sigf(pre[3]);
}

// ---------------------------------------------------------------------------

extern "C" void kernel_launch(void* const* d_in, const int* in_sizes, int n_in,
                              void* d_out, int out_size, void* d_ws, size_t ws_size,
                              hipStream_t stream) {
    const float* x    = (const float*)d_in[0];
    const float* cell = (const float*)d_in[1];
    const float* hid  = (const float*)d_in[2];
    const float* Wx   = (const float*)d_in[3];
    const float* bx   = (const float*)d_in[4];
    const float* Wh   = (const float*)d_in[5];
    const float* bh   = (const float*)d_in[6];
    float* out = (float*)d_out;

    const size_t szA = (size_t)B_ROWS * D_K * 2;    // 64 MB
    const size_t szW = (size_t)4096 * D_K * 2;      // 16 MB
    const size_t szB = 4096 * 4;
    if (ws_size < szA + szW + szB) {
        lstm_naive_kernel<<<(B_ROWS * 1024) / 256, 256, 0, stream>>>(
            x, cell, hid, Wx, bx, Wh, bh, out);
        return;
    }

    unsigned short* Ab = (unsigned short*)d_ws;
    unsigned short* Wb = (unsigned short*)((char*)d_ws + szA);
    float* bias = (float*)((char*)d_ws + szA + szW);

    pack_A_kernel<<<8192, 256, 0, stream>>>(x, hid, Ab);
    pack_W_kernel<<<2048, 256, 0, stream>>>(Wx, Wh, Wb);
    pack_bias_kernel<<<16, 256, 0, stream>>>(bx, bh, bias);

    lstm_gemm_kernel<<<1024, 512, 0, stream>>>(Ab, Wb, bias, cell, out);
}